// Round 7
// baseline (200.723 us; speedup 1.0000x reference)
//
#include <hip/hip_runtime.h>

#define B_DIM   2048
#define IN_DIM  4096
#define OUT_DIM 4096
#define FAN     64

// R7: 1024-thread blocks, 1 block/CU, 16 waves/CU (2x R3/R6 — every 64KB-block
// config measured ~8 waves/CU), 2 x 64KB LDS double-buffer, R5's proven
// one-barrier-per-tile pipeline WITHOUT R5's b64 width penalty (b128 = 8
// MACs/read kept). Buffer parity = compile-time constant (unrolled bt loop,
// base (bt&1)*65536 folds into address unpack) -> no loop-carried regs (R4
// spill lesson). __launch_bounds__(1024,4) -> 512 VGPR headroom vs ~120 live.
//
// Packed layout (d_ws): tile t = batch rows 8t..8t+7. Cell (t,c) = 16 B:
// dword k = bf16 rows (2k, 2k+1) of column c. ds_read_b128 at c*16 -> 8 rows.

typedef float v2f __attribute__((ext_vector_type(2)));

__device__ __forceinline__ unsigned bf16_rne(float f) {
    unsigned u = __float_as_uint(f);
    return (u + 0x7fffu + ((u >> 16) & 1u)) >> 16;   // round-to-nearest-even bf16
}

// ---------------- Phase 1: pack fp32 -> bf16 8-row cells ----------------
__global__ __launch_bounds__(256) void pack_kernel(
    const float* __restrict__ input, uint4* __restrict__ wsp)
{
    const int idx = blockIdx.x * 256 + threadIdx.x;   // [0, 524288): 2 cells each
    const int t   = idx >> 11;                        // tile [0,256)
    const int c0  = (idx & 2047) << 1;                // column pair [0,4096)

    const float* p = input + (size_t)t * 8 * IN_DIM + c0;
    const float2 r0 = *reinterpret_cast<const float2*>(p + 0 * IN_DIM);
    const float2 r1 = *reinterpret_cast<const float2*>(p + 1 * IN_DIM);
    const float2 r2 = *reinterpret_cast<const float2*>(p + 2 * IN_DIM);
    const float2 r3 = *reinterpret_cast<const float2*>(p + 3 * IN_DIM);
    const float2 r4 = *reinterpret_cast<const float2*>(p + 4 * IN_DIM);
    const float2 r5 = *reinterpret_cast<const float2*>(p + 5 * IN_DIM);
    const float2 r6 = *reinterpret_cast<const float2*>(p + 6 * IN_DIM);
    const float2 r7 = *reinterpret_cast<const float2*>(p + 7 * IN_DIM);

    uint4 a, b;
    a.x = bf16_rne(r0.x) | (bf16_rne(r1.x) << 16);
    a.y = bf16_rne(r2.x) | (bf16_rne(r3.x) << 16);
    a.z = bf16_rne(r4.x) | (bf16_rne(r5.x) << 16);
    a.w = bf16_rne(r6.x) | (bf16_rne(r7.x) << 16);
    b.x = bf16_rne(r0.y) | (bf16_rne(r1.y) << 16);
    b.y = bf16_rne(r2.y) | (bf16_rne(r3.y) << 16);
    b.z = bf16_rne(r4.y) | (bf16_rne(r5.y) << 16);
    b.w = bf16_rne(r6.y) | (bf16_rne(r7.y) << 16);

    uint4* q = wsp + (size_t)t * IN_DIM + c0;
    q[0] = a;
    q[1] = b;
}

// ---------------- Phase 2: double-buffered gather + accumulate ----------------
__global__ __launch_bounds__(1024, 4) void condensed_kernel(
    const uint4* __restrict__ wsp,
    const float* __restrict__ weight,
    const float* __restrict__ bias,
    const int*   __restrict__ mask,
    float*       __restrict__ out)
{
    extern __shared__ __align__(16) uint4 lds[];      // 2 x 4096 cells = 128 KB

    const int tid   = threadIdx.x;                    // [0,1024)
    const int o     = blockIdx.y * 1024 + tid;
    const int bseg  = blockIdx.x * 32;                // 32 batch rows per block
    const int tbase = bseg >> 3;                      // 4 tiles per block

    // ---- idx -> packed LDS byte addresses (2 x 16-bit / reg) + weights ----
    unsigned paddr[FAN / 2];
    float    wv[FAN];
    {
        const int4*   mv = reinterpret_cast<const int4*>(mask)     + o * (FAN / 4);
        const float4* wp = reinterpret_cast<const float4*>(weight) + o * (FAN / 4);
        #pragma unroll
        for (int j = 0; j < FAN / 4; ++j) {
            int4   m4 = mv[j];
            float4 w4 = wp[j];
            paddr[2*j+0] = ((unsigned)m4.x << 4) | ((unsigned)m4.y << 20);
            paddr[2*j+1] = ((unsigned)m4.z << 4) | ((unsigned)m4.w << 20);
            wv[4*j+0] = w4.x;
            wv[4*j+1] = w4.y;
            wv[4*j+2] = w4.z;
            wv[4*j+3] = w4.w;
        }
    }
    const float bv = bias[o];
    const char* ldsb = reinterpret_cast<const char*>(lds);

    // ---- prologue: DMA tile 0 -> buf0 (4 x 16B per thread) ----
    {
        const uint4* src = wsp + (size_t)tbase * IN_DIM + tid;
        #pragma unroll
        for (int it = 0; it < 4; ++it) {
            __builtin_amdgcn_global_load_lds(
                (const __attribute__((address_space(1))) unsigned*)(src + it * 1024),
                (__attribute__((address_space(3))) unsigned*)(lds + it * 1024 + tid),
                16, 0, 0);
        }
    }
    __syncthreads();                                  // buf0 resident

    #pragma unroll
    for (int bt = 0; bt < 4; ++bt) {                  // 4 tiles x 8 rows = 32 rows
        // ---- prefetch tile bt+1 into the spare buffer (freed at last barrier) ----
        if (bt < 3) {
            const uint4* src = wsp + (size_t)(tbase + bt + 1) * IN_DIM + tid;
            uint4*       dst = lds + ((bt + 1) & 1) * IN_DIM + tid;
            #pragma unroll
            for (int it = 0; it < 4; ++it) {
                __builtin_amdgcn_global_load_lds(
                    (const __attribute__((address_space(1))) unsigned*)(src + it * 1024),
                    (__attribute__((address_space(3))) unsigned*)(dst + it * 1024),
                    16, 0, 0);
            }
        }

        // ---- gather + accumulate on buffer (bt&1): base is compile-time ----
        const unsigned base = (unsigned)(bt & 1) << 16;   // 0 or 65536
        v2f a01 = {0.f, 0.f}, a23 = {0.f, 0.f}, a45 = {0.f, 0.f}, a67 = {0.f, 0.f};
        #pragma unroll
        for (int jj = 0; jj < FAN / 2; ++jj) {
            const unsigned pa = paddr[jj];
            const uint4 g0 = *reinterpret_cast<const uint4*>(ldsb + ((pa & 0xffffu) + base));
            const uint4 g1 = *reinterpret_cast<const uint4*>(ldsb + ((pa >> 16) + base));
            {
                const v2f w2 = {wv[2*jj+0], wv[2*jj+0]};
                v2f v;
                v.x = __uint_as_float(g0.x << 16);
                v.y = __uint_as_float(g0.x & 0xffff0000u);
                a01 = __builtin_elementwise_fma(v, w2, a01);
                v.x = __uint_as_float(g0.y << 16);
                v.y = __uint_as_float(g0.y & 0xffff0000u);
                a23 = __builtin_elementwise_fma(v, w2, a23);
                v.x = __uint_as_float(g0.z << 16);
                v.y = __uint_as_float(g0.z & 0xffff0000u);
                a45 = __builtin_elementwise_fma(v, w2, a45);
                v.x = __uint_as_float(g0.w << 16);
                v.y = __uint_as_float(g0.w & 0xffff0000u);
                a67 = __builtin_elementwise_fma(v, w2, a67);
            }
            {
                const v2f w2 = {wv[2*jj+1], wv[2*jj+1]};
                v2f v;
                v.x = __uint_as_float(g1.x << 16);
                v.y = __uint_as_float(g1.x & 0xffff0000u);
                a01 = __builtin_elementwise_fma(v, w2, a01);
                v.x = __uint_as_float(g1.y << 16);
                v.y = __uint_as_float(g1.y & 0xffff0000u);
                a23 = __builtin_elementwise_fma(v, w2, a23);
                v.x = __uint_as_float(g1.z << 16);
                v.y = __uint_as_float(g1.z & 0xffff0000u);
                a45 = __builtin_elementwise_fma(v, w2, a45);
                v.x = __uint_as_float(g1.w << 16);
                v.y = __uint_as_float(g1.w & 0xffff0000u);
                a67 = __builtin_elementwise_fma(v, w2, a67);
            }
        }

        // ---- write 8 outputs (coalesced across 1024 threads) ----
        float* op = out + (size_t)(bseg + bt * 8) * OUT_DIM + o;
        op[0 * OUT_DIM] = a01.x + bv;
        op[1 * OUT_DIM] = a01.y + bv;
        op[2 * OUT_DIM] = a23.x + bv;
        op[3 * OUT_DIM] = a23.y + bv;
        op[4 * OUT_DIM] = a45.x + bv;
        op[5 * OUT_DIM] = a45.y + bv;
        op[6 * OUT_DIM] = a67.x + bv;
        op[7 * OUT_DIM] = a67.y + bv;

        // ONE barrier: current buffer's readers done (safe to overwrite next
        // iter) AND per-wave vmcnt drain -> prefetched tile bt+1 resident.
        __syncthreads();
    }
}

extern "C" void kernel_launch(void* const* d_in, const int* in_sizes, int n_in,
                              void* d_out, int out_size, void* d_ws, size_t ws_size,
                              hipStream_t stream) {
    const float* input  = (const float*)d_in[0];
    const float* weight = (const float*)d_in[1];
    const float* bias   = (const float*)d_in[2];
    const int*   mask   = (const int*)d_in[3];
    float*       out    = (float*)d_out;
    uint4*       wsp    = (uint4*)d_ws;               // needs 16 MiB

    pack_kernel<<<2048, 256, 0, stream>>>(input, wsp);

    // 128 KB dynamic LDS opt-in (host-side, idempotent, capture-safe — proven R4).
    hipFuncSetAttribute(reinterpret_cast<const void*>(condensed_kernel),
                        hipFuncAttributeMaxDynamicSharedMemorySize, 131072);
    dim3 grid(64, 4);    // 256 blocks, 1024 thr: 1 block/CU, 16 waves/CU
    condensed_kernel<<<grid, 1024, 131072, stream>>>(wsp, weight, bias, mask, out);
}

// Round 8
// 155.770 us; speedup vs baseline: 1.2886x; 1.2886x over previous
//
#include <hip/hip_runtime.h>

#define B_DIM   2048
#define IN_DIM  4096
#define OUT_DIM 4096
#define FAN     64

// R8: inverted tiling — tile resident, addresses streamed.
//  Phase 1 (proven): pack fp32 -> bf16 8-row cells in d_ws.
//    Cell (t,c) = 16 B: dword k = bf16 rows (2k,2k+1) of tile t, column c.
//  Phase 2: ONE block per tile. Grid = 256 blocks = exactly 1/CU, 512 thr.
//    Stage the 64 KB tile once (global_load_lds), ONE barrier, then 8 phases:
//    phase ob processes neurons ob*512+tid — loads that neuron's 64 idx+w from
//    global (L2-resident, streamed), gathers 64 x ds_read_b128, writes 8 outs.
//    ZERO barriers after staging: waves drift freely, VMEM (idx/w) of one wave
//    overlaps DS (gather) of others. DS floor = 4096 wave-b128/CU x ~16 cyc
//    ~ 28 us. R3's vmcnt(0)-barrier-every-64-gathers cadence is gone.
//  Spill lessons (R2/R4/R7): 512 thr + __launch_bounds__(512,2) (the R6 combo
//    that measured 84 VGPR, no spill), addrs packed 2x16-bit, per-phase state
//    NOT loop-carried, #pragma unroll 1 on the phase loop.

typedef float v2f __attribute__((ext_vector_type(2)));

__device__ __forceinline__ unsigned bf16_rne(float f) {
    unsigned u = __float_as_uint(f);
    return (u + 0x7fffu + ((u >> 16) & 1u)) >> 16;   // round-to-nearest-even bf16
}

// ---------------- Phase 1: pack fp32 -> bf16 8-row cells ----------------
__global__ __launch_bounds__(256) void pack_kernel(
    const float* __restrict__ input, uint4* __restrict__ wsp)
{
    const int idx = blockIdx.x * 256 + threadIdx.x;   // [0, 524288): 2 cells each
    const int t   = idx >> 11;                        // tile [0,256)
    const int c0  = (idx & 2047) << 1;                // column pair [0,4096)

    const float* p = input + (size_t)t * 8 * IN_DIM + c0;
    const float2 r0 = *reinterpret_cast<const float2*>(p + 0 * IN_DIM);
    const float2 r1 = *reinterpret_cast<const float2*>(p + 1 * IN_DIM);
    const float2 r2 = *reinterpret_cast<const float2*>(p + 2 * IN_DIM);
    const float2 r3 = *reinterpret_cast<const float2*>(p + 3 * IN_DIM);
    const float2 r4 = *reinterpret_cast<const float2*>(p + 4 * IN_DIM);
    const float2 r5 = *reinterpret_cast<const float2*>(p + 5 * IN_DIM);
    const float2 r6 = *reinterpret_cast<const float2*>(p + 6 * IN_DIM);
    const float2 r7 = *reinterpret_cast<const float2*>(p + 7 * IN_DIM);

    uint4 a, b;
    a.x = bf16_rne(r0.x) | (bf16_rne(r1.x) << 16);
    a.y = bf16_rne(r2.x) | (bf16_rne(r3.x) << 16);
    a.z = bf16_rne(r4.x) | (bf16_rne(r5.x) << 16);
    a.w = bf16_rne(r6.x) | (bf16_rne(r7.x) << 16);
    b.x = bf16_rne(r0.y) | (bf16_rne(r1.y) << 16);
    b.y = bf16_rne(r2.y) | (bf16_rne(r3.y) << 16);
    b.z = bf16_rne(r4.y) | (bf16_rne(r5.y) << 16);
    b.w = bf16_rne(r6.y) | (bf16_rne(r7.y) << 16);

    uint4* q = wsp + (size_t)t * IN_DIM + c0;
    q[0] = a;
    q[1] = b;
}

// ---------------- Phase 2: tile-resident gather + accumulate ----------------
__global__ __launch_bounds__(512, 2) void condensed_kernel(
    const uint4* __restrict__ wsp,
    const float* __restrict__ weight,
    const float* __restrict__ bias,
    const int*   __restrict__ mask,
    float*       __restrict__ out)
{
    __shared__ __align__(16) uint4 lds[IN_DIM];       // 64 KB: this block's tile

    const int tid  = threadIdx.x;                     // [0,512)
    const int tile = blockIdx.x;                      // [0,256): 8 batch rows
    const int b0   = tile * 8;

    // ---- stage the tile: 8 x 16 B DMA per thread, lane-contiguous dst ----
    {
        const uint4* src = wsp + (size_t)tile * IN_DIM + tid;
        #pragma unroll
        for (int it = 0; it < 8; ++it) {
            __builtin_amdgcn_global_load_lds(
                (const __attribute__((address_space(1))) unsigned*)(src + it * 512),
                (__attribute__((address_space(3))) unsigned*)(lds + it * 512 + tid),
                16, 0, 0);
        }
    }
    __syncthreads();                                  // THE only barrier

    const char* ldsb = reinterpret_cast<const char*>(lds);

    #pragma unroll 1                                  // keep per-phase regs dead across phases
    for (int ob = 0; ob < 8; ++ob) {
        const int o = ob * 512 + tid;                 // this phase's neuron

        // ---- stream this neuron's 64 idx (packed 2x16-bit addrs) + weights ----
        unsigned paddr[FAN / 2];
        float    wv[FAN];
        {
            const int4*   mv = reinterpret_cast<const int4*>(mask)   + o * (FAN / 4);
            const float4* wp = reinterpret_cast<const float4*>(weight) + o * (FAN / 4);
            #pragma unroll
            for (int j = 0; j < FAN / 4; ++j) {
                int4   m4 = mv[j];
                float4 w4 = wp[j];
                paddr[2*j+0] = ((unsigned)m4.x << 4) | ((unsigned)m4.y << 20);
                paddr[2*j+1] = ((unsigned)m4.z << 4) | ((unsigned)m4.w << 20);
                wv[4*j+0] = w4.x;
                wv[4*j+1] = w4.y;
                wv[4*j+2] = w4.z;
                wv[4*j+3] = w4.w;
            }
        }
        const float bv = bias[o];

        // ---- gather + accumulate: 64 x ds_read_b128, no syncs ----
        v2f a01 = {0.f, 0.f}, a23 = {0.f, 0.f}, a45 = {0.f, 0.f}, a67 = {0.f, 0.f};
        #pragma unroll
        for (int jj = 0; jj < FAN / 2; ++jj) {
            const unsigned pa = paddr[jj];
            const uint4 g0 = *reinterpret_cast<const uint4*>(ldsb + (pa & 0xffffu));
            const uint4 g1 = *reinterpret_cast<const uint4*>(ldsb + (pa >> 16));
            {
                const v2f w2 = {wv[2*jj+0], wv[2*jj+0]};
                v2f v;
                v.x = __uint_as_float(g0.x << 16);
                v.y = __uint_as_float(g0.x & 0xffff0000u);
                a01 = __builtin_elementwise_fma(v, w2, a01);
                v.x = __uint_as_float(g0.y << 16);
                v.y = __uint_as_float(g0.y & 0xffff0000u);
                a23 = __builtin_elementwise_fma(v, w2, a23);
                v.x = __uint_as_float(g0.z << 16);
                v.y = __uint_as_float(g0.z & 0xffff0000u);
                a45 = __builtin_elementwise_fma(v, w2, a45);
                v.x = __uint_as_float(g0.w << 16);
                v.y = __uint_as_float(g0.w & 0xffff0000u);
                a67 = __builtin_elementwise_fma(v, w2, a67);
            }
            {
                const v2f w2 = {wv[2*jj+1], wv[2*jj+1]};
                v2f v;
                v.x = __uint_as_float(g1.x << 16);
                v.y = __uint_as_float(g1.x & 0xffff0000u);
                a01 = __builtin_elementwise_fma(v, w2, a01);
                v.x = __uint_as_float(g1.y << 16);
                v.y = __uint_as_float(g1.y & 0xffff0000u);
                a23 = __builtin_elementwise_fma(v, w2, a23);
                v.x = __uint_as_float(g1.z << 16);
                v.y = __uint_as_float(g1.z & 0xffff0000u);
                a45 = __builtin_elementwise_fma(v, w2, a45);
                v.x = __uint_as_float(g1.w << 16);
                v.y = __uint_as_float(g1.w & 0xffff0000u);
                a67 = __builtin_elementwise_fma(v, w2, a67);
            }
        }

        // ---- write 8 outputs (rows b0..b0+7, col o; coalesced over 512 thr) ----
        float* op = out + (size_t)b0 * OUT_DIM + o;
        op[0 * OUT_DIM] = a01.x + bv;
        op[1 * OUT_DIM] = a01.y + bv;
        op[2 * OUT_DIM] = a23.x + bv;
        op[3 * OUT_DIM] = a23.y + bv;
        op[4 * OUT_DIM] = a45.x + bv;
        op[5 * OUT_DIM] = a45.y + bv;
        op[6 * OUT_DIM] = a67.x + bv;
        op[7 * OUT_DIM] = a67.y + bv;
    }
}

extern "C" void kernel_launch(void* const* d_in, const int* in_sizes, int n_in,
                              void* d_out, int out_size, void* d_ws, size_t ws_size,
                              hipStream_t stream) {
    const float* input  = (const float*)d_in[0];
    const float* weight = (const float*)d_in[1];
    const float* bias   = (const float*)d_in[2];
    const int*   mask   = (const int*)d_in[3];
    float*       out    = (float*)d_out;
    uint4*       wsp    = (uint4*)d_ws;               // needs 16 MiB

    pack_kernel<<<2048, 256, 0, stream>>>(input, wsp);
    condensed_kernel<<<256, 512, 0, stream>>>(wsp, weight, bias, mask, out);
}

// Round 9
// 133.088 us; speedup vs baseline: 1.5082x; 1.1704x over previous
//
#include <hip/hip_runtime.h>

#define B_DIM   2048
#define IN_DIM  4096
#define OUT_DIM 4096
#define FAN     64

// R9 = R5's one-barrier pipeline + R6's b128 gather width + the R7 spill fix.
//  Phase 1 (proven): pack fp32 -> bf16 8-row cells in d_ws.
//    Cell (t,c) = 16 B: dword k = bf16 rows (2k,2k+1) of tile t, column c.
//  Phase 2: 512 thr, 128 KB dynamic LDS = TWO 64 KB tile buffers, grid
//    32 bsegs (64 rows = 8 tiles) x 8 oblocks = 256 blocks = exactly 1/CU.
//    idx/w loaded ONCE per block into regs (R8 lesson: streaming them per
//    phase serializes the DS pipe). Per tile: prefetch next tile into the
//    spare buffer, gather current (64 x ds_read_b128 = 8 MACs/read), ONE
//    barrier — the vmcnt drain finds a DMA issued ~8K cycles earlier.
//    Buffer parity is compile-time (two-stage loop body, R5-style): no
//    loop-carried address state (R4 lesson).
//  Spill fix (R7 diagnosis): extern __shared__ hides LDS from the allocator's
//    occupancy model -> it chased occupancy and picked 64 VGPR -> spill.
//    __launch_bounds__(512,1) caps the target at 1 wave/EU so the ~110 live
//    values get real registers.

typedef float v2f __attribute__((ext_vector_type(2)));

__device__ __forceinline__ unsigned bf16_rne(float f) {
    unsigned u = __float_as_uint(f);
    return (u + 0x7fffu + ((u >> 16) & 1u)) >> 16;   // round-to-nearest-even bf16
}

// ---------------- Phase 1: pack fp32 -> bf16 8-row cells ----------------
__global__ __launch_bounds__(256) void pack_kernel(
    const float* __restrict__ input, uint4* __restrict__ wsp)
{
    const int idx = blockIdx.x * 256 + threadIdx.x;   // [0, 524288): 2 cells each
    const int t   = idx >> 11;                        // tile [0,256)
    const int c0  = (idx & 2047) << 1;                // column pair [0,4096)

    const float* p = input + (size_t)t * 8 * IN_DIM + c0;
    const float2 r0 = *reinterpret_cast<const float2*>(p + 0 * IN_DIM);
    const float2 r1 = *reinterpret_cast<const float2*>(p + 1 * IN_DIM);
    const float2 r2 = *reinterpret_cast<const float2*>(p + 2 * IN_DIM);
    const float2 r3 = *reinterpret_cast<const float2*>(p + 3 * IN_DIM);
    const float2 r4 = *reinterpret_cast<const float2*>(p + 4 * IN_DIM);
    const float2 r5 = *reinterpret_cast<const float2*>(p + 5 * IN_DIM);
    const float2 r6 = *reinterpret_cast<const float2*>(p + 6 * IN_DIM);
    const float2 r7 = *reinterpret_cast<const float2*>(p + 7 * IN_DIM);

    uint4 a, b;
    a.x = bf16_rne(r0.x) | (bf16_rne(r1.x) << 16);
    a.y = bf16_rne(r2.x) | (bf16_rne(r3.x) << 16);
    a.z = bf16_rne(r4.x) | (bf16_rne(r5.x) << 16);
    a.w = bf16_rne(r6.x) | (bf16_rne(r7.x) << 16);
    b.x = bf16_rne(r0.y) | (bf16_rne(r1.y) << 16);
    b.y = bf16_rne(r2.y) | (bf16_rne(r3.y) << 16);
    b.z = bf16_rne(r4.y) | (bf16_rne(r5.y) << 16);
    b.w = bf16_rne(r6.y) | (bf16_rne(r7.y) << 16);

    uint4* q = wsp + (size_t)t * IN_DIM + c0;
    q[0] = a;
    q[1] = b;
}

// ---------------- shared gather body (base = compile-time buffer offset) ----
template <unsigned BASE>
__device__ __forceinline__ void gather_tile(
    const char* ldsb, const unsigned* paddr, const float* wv,
    float bv, float* op)
{
    v2f a01 = {0.f, 0.f}, a23 = {0.f, 0.f}, a45 = {0.f, 0.f}, a67 = {0.f, 0.f};
    #pragma unroll
    for (int jj = 0; jj < FAN / 2; ++jj) {
        const unsigned pa = paddr[jj];
        const uint4 g0 = *reinterpret_cast<const uint4*>(ldsb + BASE + (pa & 0xffffu));
        const uint4 g1 = *reinterpret_cast<const uint4*>(ldsb + BASE + (pa >> 16));
        {
            const v2f w2 = {wv[2*jj+0], wv[2*jj+0]};
            v2f v;
            v.x = __uint_as_float(g0.x << 16);
            v.y = __uint_as_float(g0.x & 0xffff0000u);
            a01 = __builtin_elementwise_fma(v, w2, a01);
            v.x = __uint_as_float(g0.y << 16);
            v.y = __uint_as_float(g0.y & 0xffff0000u);
            a23 = __builtin_elementwise_fma(v, w2, a23);
            v.x = __uint_as_float(g0.z << 16);
            v.y = __uint_as_float(g0.z & 0xffff0000u);
            a45 = __builtin_elementwise_fma(v, w2, a45);
            v.x = __uint_as_float(g0.w << 16);
            v.y = __uint_as_float(g0.w & 0xffff0000u);
            a67 = __builtin_elementwise_fma(v, w2, a67);
        }
        {
            const v2f w2 = {wv[2*jj+1], wv[2*jj+1]};
            v2f v;
            v.x = __uint_as_float(g1.x << 16);
            v.y = __uint_as_float(g1.x & 0xffff0000u);
            a01 = __builtin_elementwise_fma(v, w2, a01);
            v.x = __uint_as_float(g1.y << 16);
            v.y = __uint_as_float(g1.y & 0xffff0000u);
            a23 = __builtin_elementwise_fma(v, w2, a23);
            v.x = __uint_as_float(g1.z << 16);
            v.y = __uint_as_float(g1.z & 0xffff0000u);
            a45 = __builtin_elementwise_fma(v, w2, a45);
            v.x = __uint_as_float(g1.w << 16);
            v.y = __uint_as_float(g1.w & 0xffff0000u);
            a67 = __builtin_elementwise_fma(v, w2, a67);
        }
    }
    op[0 * OUT_DIM] = a01.x + bv;
    op[1 * OUT_DIM] = a01.y + bv;
    op[2 * OUT_DIM] = a23.x + bv;
    op[3 * OUT_DIM] = a23.y + bv;
    op[4 * OUT_DIM] = a45.x + bv;
    op[5 * OUT_DIM] = a45.y + bv;
    op[6 * OUT_DIM] = a67.x + bv;
    op[7 * OUT_DIM] = a67.y + bv;
}

__device__ __forceinline__ void dma_tile(const uint4* __restrict__ wsp,
                                         uint4* lds, int tile, int tid, int buf)
{
    const uint4* src = wsp + (size_t)tile * IN_DIM + tid;
    uint4*       dst = lds + buf * IN_DIM + tid;
    #pragma unroll
    for (int it = 0; it < 8; ++it) {
        __builtin_amdgcn_global_load_lds(
            (const __attribute__((address_space(1))) unsigned*)(src + it * 512),
            (__attribute__((address_space(3))) unsigned*)(dst + it * 512),
            16, 0, 0);
    }
}

// ---------------- Phase 2: double-buffered b128 gather ----------------
__global__ __launch_bounds__(512, 1) void condensed_kernel(
    const uint4* __restrict__ wsp,
    const float* __restrict__ weight,
    const float* __restrict__ bias,
    const int*   __restrict__ mask,
    float*       __restrict__ out)
{
    extern __shared__ __align__(16) uint4 lds[];      // 2 x 4096 cells = 128 KB

    const int tid   = threadIdx.x;                    // [0,512)
    const int o     = blockIdx.y * 512 + tid;
    const int bseg  = blockIdx.x * 64;                // 64 batch rows per block
    const int tbase = bseg >> 3;                      // 8 tiles per block

    // ---- idx -> packed LDS byte addresses (2 x 16-bit / reg) + weights ----
    unsigned paddr[FAN / 2];
    float    wv[FAN];
    {
        const int4*   mv = reinterpret_cast<const int4*>(mask)     + o * (FAN / 4);
        const float4* wp = reinterpret_cast<const float4*>(weight) + o * (FAN / 4);
        #pragma unroll
        for (int j = 0; j < FAN / 4; ++j) {
            int4   m4 = mv[j];
            float4 w4 = wp[j];
            paddr[2*j+0] = ((unsigned)m4.x << 4) | ((unsigned)m4.y << 20);
            paddr[2*j+1] = ((unsigned)m4.z << 4) | ((unsigned)m4.w << 20);
            wv[4*j+0] = w4.x;
            wv[4*j+1] = w4.y;
            wv[4*j+2] = w4.z;
            wv[4*j+3] = w4.w;
        }
    }
    const float bv = bias[o];
    const char* ldsb = reinterpret_cast<const char*>(lds);

    // ---- prologue: DMA tile 0 -> buf0 ----
    dma_tile(wsp, lds, tbase, tid, 0);
    __syncthreads();                                  // buf0 resident

    for (int hp = 0; hp < 4; ++hp) {                  // 4 x (stage A + stage B)
        const int t0 = hp * 2;                        // tile in buf0

        // ==== stage A: prefetch tile t0+1 -> buf1, compute buf0 ====
        dma_tile(wsp, lds, tbase + t0 + 1, tid, 1);
        gather_tile<0u>(ldsb, paddr, wv, bv,
                        out + (size_t)(bseg + 8 * t0) * OUT_DIM + o);
        __syncthreads();   // buf0 free; prefetch (issued ~8K cyc ago) drained

        // ==== stage B: prefetch tile t0+2 -> buf0, compute buf1 ====
        if (hp < 3) {
            dma_tile(wsp, lds, tbase + t0 + 2, tid, 0);
        }
        gather_tile<65536u>(ldsb, paddr, wv, bv,
                            out + (size_t)(bseg + 8 * t0 + 8) * OUT_DIM + o);
        __syncthreads();   // buf1 free; prefetch drained
    }
}

extern "C" void kernel_launch(void* const* d_in, const int* in_sizes, int n_in,
                              void* d_out, int out_size, void* d_ws, size_t ws_size,
                              hipStream_t stream) {
    const float* input  = (const float*)d_in[0];
    const float* weight = (const float*)d_in[1];
    const float* bias   = (const float*)d_in[2];
    const int*   mask   = (const int*)d_in[3];
    float*       out    = (float*)d_out;
    uint4*       wsp    = (uint4*)d_ws;               // needs 16 MiB

    pack_kernel<<<2048, 256, 0, stream>>>(input, wsp);

    // 128 KB dynamic LDS opt-in (host-side, idempotent, capture-safe — proven R4).
    hipFuncSetAttribute(reinterpret_cast<const void*>(condensed_kernel),
                        hipFuncAttributeMaxDynamicSharedMemorySize, 131072);
    dim3 grid(32, 8);    // 256 blocks, 512 thr, 128 KB LDS: exactly 1 block/CU
    condensed_kernel<<<grid, 512, 131072, stream>>>(wsp, weight, bias, mask, out);
}